// Round 1
// baseline (272.951 us; speedup 1.0000x reference)
//
#include <hip/hip_runtime.h>
#include <hip/hip_fp16.h>
#include <math.h>

#define NEG_SLOPE 0.2f
#define BSHIFT 8            // nodes per bucket = 256 (requires N < 65536 for src packing)
#define BCAP 8192           // padded per-bucket edge capacity (mean 4082, sigma 64)

typedef __attribute__((ext_vector_type(8))) short bf16x8;
typedef __attribute__((ext_vector_type(4))) float f32x4;

__device__ __forceinline__ float leaky(float e) {
    return e > 0.f ? e : NEG_SLOPE * e;
}
__device__ __forceinline__ float to_f(float x) { return x; }
__device__ __forceinline__ float to_f(__half x) { return __half2float(x); }

// ---------------- CSR build: padded-bucket counting sort ---------------------

__global__ __launch_bounds__(256) void partition_kernel(
        const int* __restrict__ src, const int* __restrict__ dst,
        int* __restrict__ bucketLen, int* __restrict__ pairs, int E, int nbk) {
    __shared__ int cnt[256];
    __shared__ int run[256];
    int t = threadIdx.x;
    int chunk = (E + gridDim.x - 1) / gridDim.x;
    int beg = blockIdx.x * chunk;
    int end = min(beg + chunk, E);
    cnt[t] = 0;
    __syncthreads();
    for (int i = beg + t; i < end; i += 256)
        atomicAdd(&cnt[dst[i] >> BSHIFT], 1);
    __syncthreads();
    if (t < nbk) run[t] = t * BCAP + atomicAdd(&bucketLen[t], cnt[t]);
    __syncthreads();
    for (int i = beg + t; i < end; i += 256) {
        int d = dst[i];
        int slot = atomicAdd(&run[d >> BSHIFT], 1);
        if (slot < (d >> BSHIFT) * BCAP + BCAP)   // overflow clamp (never fires)
            pairs[slot] = (src[i] << BSHIFT) | (d & 255);
    }
}

__device__ void csr_build_body(
        int b, const int* __restrict__ bucketLen, const int* __restrict__ pairs,
        int* __restrict__ off, int* __restrict__ degA,
        int* __restrict__ csr_src, int N) {
    __shared__ int degl[256];
    __shared__ int s[256];
    __shared__ int cur[256];
    int t = threadIdx.x;
    int n0 = b << BSHIFT;
    int nodecnt = min(256, N - n0);
    int ebeg = b * BCAP;
    int eend = ebeg + bucketLen[b];

    degl[t] = 0;
    __syncthreads();
    for (int i = ebeg + t; i < eend; i += 256)
        atomicAdd(&degl[pairs[i] & 255], 1);
    __syncthreads();

    int v = degl[t];
    s[t] = v;
    __syncthreads();
    for (int o = 1; o < 256; o <<= 1) {
        int x = (t >= o) ? s[t - o] : 0;
        __syncthreads();
        s[t] += x;
        __syncthreads();
    }
    int excl = s[t] - v;
    if (t < nodecnt) {
        off[n0 + t] = ebeg + excl;
        degA[n0 + t] = v;
    }
    cur[t] = excl;
    __syncthreads();

    for (int i = ebeg + t; i < eend; i += 256) {
        int pk = pairs[i];
        int p = atomicAdd(&cur[pk & 255], 1);
        csr_src[ebeg + p] = pk >> BSHIFT;
    }
}

// ---------------- W pre-split into bf16 hi/lo, MFMA B-fragment order ---------

__device__ __forceinline__ unsigned f2bf_bits(float x) {
    unsigned u = __float_as_uint(x);
    return (u + 0x7fffu + ((u >> 16) & 1u)) >> 16;
}

__global__ __launch_bounds__(256) void pack_w3_kernel(
        const float* __restrict__ W0, const float* __restrict__ W1,
        const float* __restrict__ W2, short* __restrict__ Whi,
        short* __restrict__ Wlo, int* __restrict__ bucketLen) {
    int idx = blockIdx.x * 256 + threadIdx.x;   // 16384 total
    if (idx < 256) bucketLen[idx] = 0;
    if (idx >= 16384) return;
    const float* W;
    int base, li;
    if (idx < 8192)       { W = W0; base = 0;     li = idx; }
    else if (idx < 12288) { W = W1; base = 8192;  li = idx - 8192; }
    else                  { W = W2; base = 12288; li = idx - 12288; }
    int k = li >> 6, col = li & 63;
    int c = k >> 5, kin = k & 31;
    int g = col >> 4, nn = col & 15;
    float x = W[li];
    unsigned hb = f2bf_bits(x);
    float hf = __uint_as_float(hb << 16);
    unsigned lb = f2bf_bits(x - hf);
    int o = base + (((c * 4 + g) * 16 + nn) << 5) + kin;
    Whi[o] = (short)hb;
    Wlo[o] = (short)lb;
}

// ---------------- GEMM + alpha epilogue (MFMA, split-bf16) ----------------

template <int CIN, typename InT>
__device__ void gemm_body(
        int bid, const InT* __restrict__ h, const short* __restrict__ Whi,
        const short* __restrict__ Wlo,
        const float* __restrict__ a_src, const float* __restrict__ a_dst,
        __half* __restrict__ hp, float* __restrict__ as_, float* __restrict__ ad_,
        int n) {
    constexpr int KC = CIN / 32;
    int t = threadIdx.x, wave = t >> 6, lane = t & 63;
    int quad = lane >> 4, l16 = lane & 15;
    int node0 = bid * 64 + wave * 16;

    f32x4 acc[4];
#pragma unroll
    for (int g = 0; g < 4; ++g) acc[g] = (f32x4){0.f, 0.f, 0.f, 0.f};

    int nodeA = node0 + l16;
    bool va = nodeA < n;
    const InT* hrow = h + (size_t)(va ? nodeA : 0) * CIN + quad * 8;

#pragma unroll
    for (int c = 0; c < KC; ++c) {
        bf16x8 bhi[4], blo[4];
#pragma unroll
        for (int g = 0; g < 4; ++g) {
            int o = (((c * 4 + g) * 16 + l16) << 5) + quad * 8;
            bhi[g] = *(const bf16x8*)(Whi + o);
            blo[g] = *(const bf16x8*)(Wlo + o);
        }
        bf16x8 ahi, alo;
#pragma unroll
        for (int j = 0; j < 8; ++j) {
            float x = va ? to_f(hrow[c * 32 + j]) : 0.f;
            unsigned hb = f2bf_bits(x);
            float hf = __uint_as_float(hb << 16);
            unsigned lb = f2bf_bits(x - hf);
            ahi[j] = (short)hb;
            alo[j] = (short)lb;
        }
#pragma unroll
        for (int g = 0; g < 4; ++g) {
            acc[g] = __builtin_amdgcn_mfma_f32_16x16x32_bf16(ahi, bhi[g], acc[g], 0, 0, 0);
            acc[g] = __builtin_amdgcn_mfma_f32_16x16x32_bf16(ahi, blo[g], acc[g], 0, 0, 0);
            acc[g] = __builtin_amdgcn_mfma_f32_16x16x32_bf16(alo, bhi[g], acc[g], 0, 0, 0);
        }
    }

    float as4[4], ad4[4];
#pragma unroll
    for (int g = 0; g < 4; ++g) {
        as4[g] = a_src[g * 16 + l16];
        ad4[g] = a_dst[g * 16 + l16];
    }
#pragma unroll
    for (int r = 0; r < 4; ++r) {
        int node = node0 + quad * 4 + r;
        bool v = node < n;
        float vs = 0.f, vd = 0.f;
#pragma unroll
        for (int g = 0; g < 4; ++g) {
            float val = acc[g][r];
            if (v) hp[(size_t)node * 64 + g * 16 + l16] = __float2half_rn(val);
            vs = fmaf(val, as4[g], vs);
            vd = fmaf(val, ad4[g], vd);
        }
#pragma unroll
        for (int o = 1; o <= 8; o <<= 1) {
            vs += __shfl_xor(vs, o);
            vd += __shfl_xor(vd, o);
        }
        if (v && l16 == 0) {
            as_[node] = vs;
            ad_[node] = vd;
        }
    }
}

// fused: blocks [0,nbk) build CSR (196 blocks would otherwise run alone at
// <1 block/CU), blocks [nbk, nbk+gb) run the layer-0 GEMM. Independent work.
__global__ __launch_bounds__(256) void csr_gemm0_kernel(
        const int* __restrict__ bucketLen, const int* __restrict__ pairs,
        int* __restrict__ off, int* __restrict__ degA, int* __restrict__ csr_src,
        int N, int nbk,
        const float* __restrict__ x, const short* __restrict__ Whi,
        const short* __restrict__ Wlo, const float* __restrict__ a_src,
        const float* __restrict__ a_dst, __half* __restrict__ hp,
        float* __restrict__ as_, float* __restrict__ ad_) {
    if ((int)blockIdx.x < nbk)
        csr_build_body(blockIdx.x, bucketLen, pairs, off, degA, csr_src, N);
    else
        gemm_body<128, float>((int)blockIdx.x - nbk, x, Whi, Wlo, a_src, a_dst,
                              hp, as_, ad_, N);
}

template <int CIN, typename InT>
__global__ __launch_bounds__(256) void gemm_mfma_kernel(
        const InT* __restrict__ h, const short* __restrict__ Whi,
        const short* __restrict__ Wlo,
        const float* __restrict__ a_src, const float* __restrict__ a_dst,
        __half* __restrict__ hp, float* __restrict__ as_, float* __restrict__ ad_,
        int n) {
    gemm_body<CIN, InT>((int)blockIdx.x, h, Whi, Wlo, a_src, a_dst, hp, as_, ad_, n);
}

// ---------------- per-dst segment softmax + weighted gather-sum ----------------
// Two nodes per wave (32 lanes each): doubles logit-phase lane utilization,
// shrinks shuffle trees to 5 xors, and the gather loop issues 4 independent
// row loads per batch to cover L2 latency. All shuffles use xor masks <=16 so
// the two half-waves never interact (safe under half-wave divergence).

__device__ __forceinline__ void h4_to_f(uint2 u, float* f) {
    __half2 a = *(__half2*)&u.x;
    __half2 b = *(__half2*)&u.y;
    float2 f01 = __half22float2(a);
    float2 f23 = __half22float2(b);
    f[0] = f01.x; f[1] = f01.y; f[2] = f23.x; f[3] = f23.y;
}

__device__ __forceinline__ void store_row(float* out, size_t idx, float4 r) {
    ((float4*)out)[idx] = r;
}
__device__ __forceinline__ void store_row(__half* out, size_t idx, float4 r) {
    __half2 a = __floats2half2_rn(r.x, r.y);
    __half2 b = __floats2half2_rn(r.z, r.w);
    uint2 u;
    u.x = *(unsigned*)&a;
    u.y = *(unsigned*)&b;
    ((uint2*)out)[idx] = u;
}
__device__ __forceinline__ void store_el(float* out, size_t idx, float v) { out[idx] = v; }
__device__ __forceinline__ void store_el(__half* out, size_t idx, float v) { out[idx] = __float2half_rn(v); }

template <typename OutT>
__global__ __launch_bounds__(256) void agg_kernel(
        const __half* __restrict__ hp,
        const float* __restrict__ as_, const float* __restrict__ ad_,
        const int* __restrict__ off, const int* __restrict__ degA,
        const int* __restrict__ csr_src,
        const float* __restrict__ bias, OutT* __restrict__ out, int n) {
    __shared__ float pw[4][64];
    __shared__ int ps[4][64];
    int t = threadIdx.x;
    int wave = t >> 6, lane = t & 63;
    int hf = lane >> 5, l32 = lane & 31;
    int node = blockIdx.x * 8 + wave * 2 + hf;
    if (node >= n) return;

    int beg = off[node];
    int deg = degA[node];
    int end = beg + deg;
    float adst = ad_[node];
    float e_self = leaky(as_[node] + adst);

    if (deg <= 32) {
        bool valid = l32 < deg;
        int s = valid ? csr_src[beg + l32] : 0;
        float e = valid ? leaky(as_[s] + adst) : -3.4e38f;

        float m = e;
#pragma unroll
        for (int o = 16; o > 0; o >>= 1) m = fmaxf(m, __shfl_xor(m, o));
        m = fmaxf(m, e_self);

        float p = valid ? __expf(e - m) : 0.f;
        float pself = __expf(e_self - m);
        float se = p;
#pragma unroll
        for (int o = 16; o > 0; o >>= 1) se += __shfl_xor(se, o);
        se += pself;
        float inv = 1.0f / (se + 1e-16f);
        p *= inv;

        pw[wave][lane] = p;    // lane = hf*32 + l32
        ps[wave][lane] = s;

        int group = l32 >> 4, sub = l32 & 15;
        const uint2* hp2 = (const uint2*)hp;   // row = 16 x uint2 (64 halves)

        float wself = (group == 0) ? pself * inv : 0.f;
        float hv[4];
        h4_to_f(hp2[(size_t)node * 16 + sub], hv);
        float ax = wself * hv[0], ay = wself * hv[1];
        float az = wself * hv[2], aw = wself * hv[3];

        // group g of this half handles edges g, g+2, g+4, ... in batches of 4:
        // 4 independent row loads issued together, then 16 FMAs.
        int base = hf * 32;
        for (int j = group; j < deg; j += 8) {
            float w4[4];
            uint2 u4[4];
#pragma unroll
            for (int q = 0; q < 4; ++q) {
                int jj = j + 2 * q;
                bool ok = jj < deg;
                w4[q] = ok ? pw[wave][base + jj] : 0.f;
                u4[q] = ok ? hp2[(size_t)ps[wave][base + jj] * 16 + sub]
                           : make_uint2(0u, 0u);
            }
#pragma unroll
            for (int q = 0; q < 4; ++q) {
                float f[4];
                h4_to_f(u4[q], f);
                ax = fmaf(w4[q], f[0], ax);
                ay = fmaf(w4[q], f[1], ay);
                az = fmaf(w4[q], f[2], az);
                aw = fmaf(w4[q], f[3], aw);
            }
        }

        // combine the 2 groups of this half
        ax += __shfl_xor(ax, 16);
        ay += __shfl_xor(ay, 16);
        az += __shfl_xor(az, 16);
        aw += __shfl_xor(aw, 16);

        float4 b4 = ((const float4*)bias)[sub];
        float4 r;
        r.x = ax + b4.x; r.x = r.x > 0.f ? r.x : 0.f;
        r.y = ay + b4.y; r.y = r.y > 0.f ? r.y : 0.f;
        r.z = az + b4.z; r.z = r.z > 0.f ? r.z : 0.f;
        r.w = aw + b4.w; r.w = r.w > 0.f ? r.w : 0.f;
        if (group == 0) store_row(out, (size_t)node * 16 + sub, r);
    } else {
        // 32-lane strided fallback (P(deg>32) ~ 8e-5 per node)
        float mymax = e_self;
        for (int i = beg + l32; i < end; i += 32) {
            int s = csr_src[i];
            mymax = fmaxf(mymax, leaky(as_[s] + adst));
        }
#pragma unroll
        for (int o = 16; o > 0; o >>= 1) mymax = fmaxf(mymax, __shfl_xor(mymax, o));
        float m = mymax;

        float se = 0.f;
        for (int i = beg + l32; i < end; i += 32) {
            int s = csr_src[i];
            se += __expf(leaky(as_[s] + adst) - m);
        }
#pragma unroll
        for (int o = 16; o > 0; o >>= 1) se += __shfl_xor(se, o);
        se += __expf(e_self - m);
        float inv = 1.0f / (se + 1e-16f);

        // each lane owns 2 columns
        const __half2* hpx = (const __half2*)hp;   // row = 32 x half2
        float2 hs = __half22float2(hpx[(size_t)node * 32 + l32]);
        float wself = __expf(e_self - m) * inv;
        float a0 = wself * hs.x, a1 = wself * hs.y;
        for (int i = beg; i < end; ++i) {
            int s = csr_src[i];
            float w = __expf(leaky(as_[s] + adst) - m) * inv;
            float2 hv = __half22float2(hpx[(size_t)s * 32 + l32]);
            a0 = fmaf(w, hv.x, a0);
            a1 = fmaf(w, hv.y, a1);
        }
        float r0 = a0 + bias[l32 * 2];
        float r1 = a1 + bias[l32 * 2 + 1];
        store_el(out, (size_t)node * 64 + l32 * 2,     r0 > 0.f ? r0 : 0.f);
        store_el(out, (size_t)node * 64 + l32 * 2 + 1, r1 > 0.f ? r1 : 0.f);
    }
}

// ---------------- launch ----------------

extern "C" void kernel_launch(void* const* d_in, const int* in_sizes, int n_in,
                              void* d_out, int out_size, void* d_ws, size_t ws_size,
                              hipStream_t stream) {
    const float* x = (const float*)d_in[0];
    const int* edge_index = (const int*)d_in[1];
    const int N = in_sizes[0] / 128;
    const int E = in_sizes[1] / 2;
    const int NBK = (N + 255) >> BSHIFT;

    const float* W[3]    = {(const float*)d_in[4], (const float*)d_in[8],  (const float*)d_in[12]};
    const float* asrc[3] = {(const float*)d_in[5], (const float*)d_in[9],  (const float*)d_in[13]};
    const float* adst[3] = {(const float*)d_in[6], (const float*)d_in[10], (const float*)d_in[14]};
    const float* bias[3] = {(const float*)d_in[7], (const float*)d_in[11], (const float*)d_in[15]};

    char* ws = (char*)d_ws;
    size_t o = 0;
    auto alloc = [&](size_t bytes) {
        char* p = ws + o;
        o += (bytes + 255) & ~(size_t)255;
        return p;
    };
    int* bucketLen    = (int*)alloc(256 * 4);
    int* pairs        = (int*)alloc((size_t)NBK * BCAP * 4);
    int* off          = (int*)alloc((size_t)N * 4);
    int* degA         = (int*)alloc((size_t)N * 4);
    int* csr_src      = (int*)alloc((size_t)NBK * BCAP * 4);
    float* as_        = (float*)alloc((size_t)N * 4);
    float* ad_        = (float*)alloc((size_t)N * 4);
    __half* hpbuf     = (__half*)alloc((size_t)N * 64 * 2);
    __half* actB      = (__half*)alloc((size_t)N * 64 * 2);
    short* Whi        = (short*)alloc(16384 * 2);
    short* Wlo        = (short*)alloc(16384 * 2);

    const int* srcp = edge_index;
    const int* dstp = edge_index + E;

    int gb = (N + 63) / 64;
    int ab = (N + 7) / 8;

    pack_w3_kernel<<<64, 256, 0, stream>>>(W[0], W[1], W[2], Whi, Wlo, bucketLen);
    partition_kernel<<<1024, 256, 0, stream>>>(srcp, dstp, bucketLen, pairs, E, NBK);

    // fused CSR-build + layer-0 GEMM (independent work, overlapped)
    csr_gemm0_kernel<<<NBK + gb, 256, 0, stream>>>(
        bucketLen, pairs, off, degA, csr_src, N, NBK,
        x, Whi, Wlo, asrc[0], adst[0], hpbuf, as_, ad_);
    agg_kernel<__half><<<ab, 256, 0, stream>>>(
        hpbuf, as_, ad_, off, degA, csr_src, bias[0], actB, N);

    // layer 1: fp16 in, fp16 out
    gemm_mfma_kernel<64, __half><<<gb, 256, 0, stream>>>(
        actB, Whi + 8192, Wlo + 8192, asrc[1], adst[1], hpbuf, as_, ad_, N);
    agg_kernel<__half><<<ab, 256, 0, stream>>>(
        hpbuf, as_, ad_, off, degA, csr_src, bias[1], actB, N);

    // layer 2: fp16 in, f32 final out
    gemm_mfma_kernel<64, __half><<<gb, 256, 0, stream>>>(
        actB, Whi + 12288, Wlo + 12288, asrc[2], adst[2], hpbuf, as_, ad_, N);
    agg_kernel<float><<<ab, 256, 0, stream>>>(
        hpbuf, as_, ad_, off, degA, csr_src, bias[2], (float*)d_out, N);
}